// Round 1
// 328.532 us; speedup vs baseline: 1.0087x; 1.0087x over previous
//
#include <hip/hip_runtime.h>
#include <math.h>

#define EPS 1e-12f

typedef unsigned short ushort_t;
typedef __attribute__((ext_vector_type(8))) short short8;
typedef __attribute__((ext_vector_type(4))) float f32x4;
typedef __attribute__((ext_vector_type(4))) unsigned short ushort4v;
typedef __attribute__((ext_vector_type(2))) unsigned int uint2v;

// ---- workspace layout (float units) ----
#define WS_WB_F 0
#define WS_WO_F 24576
#define WS_TH_F 40960
#define WS_PH_F 1089536
#define WS_G_F  1351680

__device__ __forceinline__ ushort_t f2bf(float f) {
  unsigned int u = __float_as_uint(f);
  u += 0x7fffu + ((u >> 16) & 1u);
  return (ushort_t)(u >> 16);
}
__device__ __forceinline__ float bf2f(ushort_t u) {
  return __uint_as_float(((unsigned int)u) << 16);
}
__device__ __forceinline__ unsigned int pack_bf2(float lo, float hi) {
  return (unsigned int)f2bf(lo) | ((unsigned int)f2bf(hi) << 16);
}

__device__ __forceinline__ float block_reduce_sum(float v, float* red) {
  int t = threadIdx.x;
  red[t] = v;
  __syncthreads();
  #pragma unroll
  for (int s = 128; s > 0; s >>= 1) {
    if (t < s) red[t] += red[t + s];
    __syncthreads();
  }
  float r = red[0];
  __syncthreads();
  return r;
}

// One block per weight: spectral-norm scale, emit bf16 weights.
__global__ __launch_bounds__(256) void sn_kernel(
    const float* __restrict__ Wt, const float* __restrict__ Wp,
    const float* __restrict__ Wg, const float* __restrict__ Wo,
    const float* __restrict__ ut, const float* __restrict__ up,
    const float* __restrict__ ug, const float* __restrict__ uo,
    float* __restrict__ ws) {
  __shared__ float red[256];
  __shared__ float ub[256];
  __shared__ float vb[256];
  const float* W; const float* u; int O, Ci;
  switch (blockIdx.x) {
    case 0:  W = Wt; u = ut; O = 32;  Ci = 256; break;
    case 1:  W = Wp; u = up; O = 32;  Ci = 256; break;
    case 2:  W = Wg; u = ug; O = 128; Ci = 256; break;
    default: W = Wo; u = uo; O = 256; Ci = 128; break;
  }
  int t = threadIdx.x;
  if (t < O) ub[t] = u[t];
  __syncthreads();
  float tv = 0.f;
  if (t < Ci) {
    for (int o = 0; o < O; o++) tv += W[o * Ci + t] * ub[o];
  }
  float nt2 = block_reduce_sum((t < Ci) ? tv * tv : 0.f, red);
  float ntn = sqrtf(nt2);
  if (t < Ci) vb[t] = tv / (ntn + EPS);
  __syncthreads();
  float sv = 0.f;
  if (t < O) {
    for (int c = 0; c < Ci; c++) sv += W[t * Ci + c] * vb[c];
  }
  float ss = block_reduce_sum((t < O) ? sv * sv : 0.f, red);
  float ns = sqrtf(ss);
  float sigma = ss / (ns + EPS);
  float inv = 1.f / sigma;
  int total = O * Ci;
  ushort_t* dst;
  if (blockIdx.x == 3)      dst = (ushort_t*)(ws + WS_WO_F);
  else if (blockIdx.x == 0) dst = (ushort_t*)(ws + WS_WB_F);
  else if (blockIdx.x == 1) dst = (ushort_t*)(ws + WS_WB_F) + 32 * 256;
  else                      dst = (ushort_t*)(ws + WS_WB_F) + 64 * 256;
  for (int i = t; i < total; i += 256) dst[i] = f2bf(W[i] * inv);
}

// Fused projection GEMM (unchanged this round).
__global__ __launch_bounds__(256, 2) void proj_mfma(
    const float* __restrict__ x, const ushort_t* __restrict__ wb,
    ushort_t* __restrict__ theta_b, ushort_t* __restrict__ phi_b,
    ushort_t* __restrict__ g_b) {
  __shared__ ushort_t xb[128 * 264];
  const int t = threadIdx.x;
  const int n = blockIdx.y;
  const int l0 = blockIdx.x * 128;
  const float* xn = x + ((size_t)n * 256) * 4096 + l0;
  {
    const int lrel = t & 127;
    const int half = t >> 7;
    #pragma unroll 4
    for (int ch = 0; ch < 16; ++ch) {
      int chunk = half * 16 + ch;
      short8 v;
      #pragma unroll
      for (int j = 0; j < 8; ++j) {
        float f = xn[(size_t)(chunk * 8 + j) * 4096 + lrel];
        v[j] = (short)f2bf(f);
      }
      *(short8*)(&xb[lrel * 264 + chunk * 8]) = v;
    }
  }
  __syncthreads();
  const int w = t >> 6;
  const int lane = t & 63;
  const int quad = lane >> 4;
  const int l16 = lane & 15;
  const int rowA = (w * 16 + l16) * 264;
  const int rowB = (64 + w * 16 + l16) * 264;
  const int hd = blockIdx.x;
  #pragma unroll 1
  for (int pass = 0; pass < 2; ++pass) {
    f32x4 accA[6], accB[6];
    #pragma unroll
    for (int i = 0; i < 6; ++i) {
      accA[i] = (f32x4){0.f, 0.f, 0.f, 0.f};
      accB[i] = (f32x4){0.f, 0.f, 0.f, 0.f};
    }
    #pragma unroll
    for (int kc = 0; kc < 8; ++kc) {
      short8 bA = *(const short8*)(&xb[rowA + kc * 32 + quad * 8]);
      short8 bB = *(const short8*)(&xb[rowB + kc * 32 + quad * 8]);
      #pragma unroll
      for (int mt = 0; mt < 6; ++mt) {
        int mtg = pass * 6 + mt;
        short8 aW = *(const short8*)(wb + (size_t)(mtg * 16 + l16) * 256 + kc * 32 + quad * 8);
        accA[mt] = __builtin_amdgcn_mfma_f32_16x16x32_bf16(aW, bA, accA[mt], 0, 0, 0);
        accB[mt] = __builtin_amdgcn_mfma_f32_16x16x32_bf16(aW, bB, accB[mt], 0, 0, 0);
      }
    }
    #pragma unroll
    for (int mt = 0; mt < 6; ++mt) {
      int mtg = pass * 6 + mt;
      if (mtg < 2) {
        int lA = l0 + w * 16 + l16;
        ushort4v vA, vB;
        #pragma unroll
        for (int r = 0; r < 4; ++r) { vA[r] = f2bf(accA[mt][r]); vB[r] = f2bf(accB[mt][r]); }
        *(ushort4v*)(theta_b + ((size_t)n * 4096 + lA) * 32 + mtg * 16 + quad * 4) = vA;
        *(ushort4v*)(theta_b + ((size_t)n * 4096 + lA + 64) * 32 + mtg * 16 + quad * 4) = vB;
      } else {
        float pm[4];
        #pragma unroll
        for (int r = 0; r < 4; ++r) {
          float v = fmaxf(accA[mt][r], accB[mt][r]);
          v = fmaxf(v, __shfl_xor(v, 1));
          pm[r] = v;
        }
        if ((l16 & 1) == 0) {
          int m = hd * 32 + w * 8 + (l16 >> 1);
          if (mtg < 4) {
            ushort4v vv;
            #pragma unroll
            for (int r = 0; r < 4; ++r) vv[r] = f2bf(pm[r]);
            *(ushort4v*)(phi_b + ((size_t)n * 1024 + m) * 32 + (mtg - 2) * 16 + quad * 4) = vv;
          } else {
            int cg0 = (mtg - 4) * 16 + quad * 4;
            #pragma unroll
            for (int r = 0; r < 4; ++r)
              g_b[((size_t)n * 128 + cg0 + r) * 1024 + m] = f2bf(pm[r]);
          }
        }
      }
    }
  }
}

// Flash attention v2: swapped-operand scores (S^T), lane-local softmax state,
// 128-key chunks, packed-dword P^T staging (2x ds_write_b64 + 1x ds_read_b128
// per 32 keys), O^T accumulation (scalar alpha rescale), XCD-aware swizzle.
__global__ __launch_bounds__(256, 3) void attn_mfma(
    const float* __restrict__ x,
    const ushort_t* __restrict__ theta_b,
    const ushort_t* __restrict__ phi_b,
    const ushort_t* __restrict__ g_b,
    const ushort_t* __restrict__ Wo_b,
    const float* __restrict__ gamma_p,
    float* __restrict__ out) {
  __shared__ ushort_t outb[256 * 68];          // 34816 B
  __shared__ unsigned int pstage[4][16 * 20];  // per-wave packed staging, 5120 B

  const int t = threadIdx.x;
  const int w = t >> 6;
  const int lane = t & 63;
  const int quad = lane >> 4;
  const int l16 = lane & 15;

  // XCD swizzle: 8 XCDs x 128 blocks; each XCD owns 2 images (g+phi L2-hot).
  const int flat = blockIdx.y * 64 + blockIdx.x;           // 0..1023
  const int nf = ((flat & 7) << 7) | (flat >> 3);          // bijective
  const int n = nf >> 6;
  const int l0 = (nf & 63) << 6;
  const int lq = l0 + w * 16;
  unsigned int* pw = pstage[w];

  // theta fragment (B operand of S^T mfma): B[c=quad*8+j][q=l16]
  const short8 b_th = *(const short8*)(theta_b + ((size_t)n * 4096 + lq + l16) * 32 + quad * 8);
  const ushort_t* phiN = phi_b + (size_t)n * 1024 * 32;
  const ushort_t* gN   = g_b + (size_t)n * 128 * 1024;

  // O^T accumulator: oacc[j][r] = O^T[c = 16j + quad*4 + r][q = l16]
  f32x4 oacc[8];
  #pragma unroll
  for (int j = 0; j < 8; ++j) oacc[j] = (f32x4){0.f, 0.f, 0.f, 0.f};
  float M = -3.0e38f, L = 0.f;   // per-lane scalars (query = l16)

  #pragma unroll 1
  for (int mc = 0; mc < 8; ++mc) {          // 128 keys per chunk
    const int m0 = mc * 128;
    // ---- scores S^T: st[i][r] = S[q=l16][key = m0 + 16i + quad*4 + r] ----
    f32x4 st[8];
    const f32x4 z = (f32x4){0.f, 0.f, 0.f, 0.f};
    #pragma unroll
    for (int i = 0; i < 8; ++i) {
      short8 aph = *(const short8*)(phiN + (size_t)(m0 + i * 16 + l16) * 32 + quad * 8);
      st[i] = __builtin_amdgcn_mfma_f32_16x16x32_bf16(aph, b_th, z, 0, 0, 0);
    }
    // ---- softmax: 31 in-lane fmax + 2 shuffles ----
    f32x4 m4 = st[0];
    #pragma unroll
    for (int i = 1; i < 8; ++i) {
      #pragma unroll
      for (int r = 0; r < 4; ++r) m4[r] = fmaxf(m4[r], st[i][r]);
    }
    float mx = fmaxf(fmaxf(m4[0], m4[1]), fmaxf(m4[2], m4[3]));
    mx = fmaxf(mx, __shfl_xor(mx, 16));
    mx = fmaxf(mx, __shfl_xor(mx, 32));
    float nm = fmaxf(M, mx);
    float alpha = __expf(M - nm);
    M = nm;
    #pragma unroll
    for (int i = 0; i < 8; ++i) {
      #pragma unroll
      for (int r = 0; r < 4; ++r) st[i][r] = __expf(st[i][r] - nm);
    }
    f32x4 s4 = st[0];
    #pragma unroll
    for (int i = 1; i < 8; ++i) {
      #pragma unroll
      for (int r = 0; r < 4; ++r) s4[r] += st[i][r];
    }
    float psum = (s4[0] + s4[1]) + (s4[2] + s4[3]);
    psum += __shfl_xor(psum, 16);
    psum += __shfl_xor(psum, 32);
    L = L * alpha + psum;
    #pragma unroll
    for (int j = 0; j < 8; ++j) {
      #pragma unroll
      for (int r = 0; r < 4; ++r) oacc[j][r] *= alpha;
    }
    // ---- pack P to bf16 dwords (frees st) ----
    unsigned int pk[16];
    #pragma unroll
    for (int i = 0; i < 8; ++i) {
      pk[2 * i]     = pack_bf2(st[i][0], st[i][1]);
      pk[2 * i + 1] = pack_bf2(st[i][2], st[i][3]);
    }
    // ---- PV: per 32-key sub-chunk, O^T += g * P^T ----
    #pragma unroll
    for (int s = 0; s < 4; ++s) {
      short8 gf[8];
      #pragma unroll
      for (int j = 0; j < 8; ++j)
        gf[j] = *(const short8*)(gN + (size_t)(j * 16 + l16) * 1024 + m0 + s * 32 + quad * 8);
      // stage P^T[key][q] packed: dword kd ↦ keys {2kd, 2kd+1} of query l16
      *(uint2v*)&pw[l16 * 20 + quad * 2]     = (uint2v){pk[4 * s],     pk[4 * s + 1]};
      *(uint2v*)&pw[l16 * 20 + 8 + quad * 2] = (uint2v){pk[4 * s + 2], pk[4 * s + 3]};
      short8 pb = *(const short8*)&pw[l16 * 20 + quad * 4];  // B[k=quad*8+j][q=l16]
      #pragma unroll
      for (int j = 0; j < 8; ++j)
        oacc[j] = __builtin_amdgcn_mfma_f32_16x16x32_bf16(gf[j], pb, oacc[j], 0, 0, 0);
    }
  }

  // ---- epilogue: D2[q][oc] = (O[q][cg]/L[q]) . Wo[oc][cg] ----
  const float invL = 1.f / L;   // per-lane (q = l16)
  f32x4 acc2[16];
  #pragma unroll
  for (int i = 0; i < 16; ++i) acc2[i] = (f32x4){0.f, 0.f, 0.f, 0.f};
  #pragma unroll
  for (int kc = 0; kc < 4; ++kc) {
    unsigned int e0 = pack_bf2(oacc[2 * kc][0] * invL, oacc[2 * kc][1] * invL);
    unsigned int e1 = pack_bf2(oacc[2 * kc][2] * invL, oacc[2 * kc][3] * invL);
    unsigned int e2 = pack_bf2(oacc[2 * kc + 1][0] * invL, oacc[2 * kc + 1][1] * invL);
    unsigned int e3 = pack_bf2(oacc[2 * kc + 1][2] * invL, oacc[2 * kc + 1][3] * invL);
    *(uint2v*)&pw[l16 * 20 + quad * 2]     = (uint2v){e0, e1};
    *(uint2v*)&pw[l16 * 20 + 8 + quad * 2] = (uint2v){e2, e3};
    short8 aO = *(const short8*)&pw[l16 * 20 + quad * 4];  // A[q=l16][cg_local=quad*8+j]
    #pragma unroll
    for (int oct = 0; oct < 16; ++oct) {
      short8 bw = *(const short8*)(Wo_b + (size_t)(oct * 16 + l16) * 128 + kc * 32 + quad * 8);
      acc2[oct] = __builtin_amdgcn_mfma_f32_16x16x32_bf16(aO, bw, acc2[oct], 0, 0, 0);
    }
  }
  // stage D2 into outb[oc][l-rel]: lane holds (q=quad*4+r, oc=oct*16+l16)
  #pragma unroll
  for (int oct = 0; oct < 16; ++oct) {
    #pragma unroll
    for (int r = 0; r < 4; ++r)
      outb[(oct * 16 + l16) * 68 + w * 16 + quad * 4 + r] = f2bf(acc2[oct][r]);
  }
  __syncthreads();
  // ---- residual + coalesced stores ----
  {
    const float gm = gamma_p[0];
    const int oc = (t >> 4);
    const int lch = (t & 15) * 4;
    #pragma unroll
    for (int ocg = 0; ocg < 16; ++ocg) {
      int row = ocg * 16 + oc;
      ushort4v ov = *(const ushort4v*)(&outb[row * 68 + lch]);
      const float* xp = x + ((size_t)n * 256 + row) * 4096 + l0 + lch;
      float* op = out + ((size_t)n * 256 + row) * 4096 + l0 + lch;
      float4 xv = *(const float4*)xp;
      float4 v;
      v.x = xv.x + gm * bf2f(ov[0]);
      v.y = xv.y + gm * bf2f(ov[1]);
      v.z = xv.z + gm * bf2f(ov[2]);
      v.w = xv.w + gm * bf2f(ov[3]);
      *(float4*)op = v;
    }
  }
}

extern "C" void kernel_launch(void* const* d_in, const int* in_sizes, int n_in,
                              void* d_out, int out_size, void* d_ws, size_t ws_size,
                              hipStream_t stream) {
  const float* x  = (const float*)d_in[0];
  const float* Wt = (const float*)d_in[1];
  const float* Wp = (const float*)d_in[2];
  const float* Wg = (const float*)d_in[3];
  const float* Wo = (const float*)d_in[4];
  const float* ut = (const float*)d_in[5];
  const float* up = (const float*)d_in[6];
  const float* ug = (const float*)d_in[7];
  const float* uo = (const float*)d_in[8];
  const float* gamma = (const float*)d_in[9];
  float* ws  = (float*)d_ws;
  float* out = (float*)d_out;

  ushort_t* wb      = (ushort_t*)(ws + WS_WB_F);
  ushort_t* Wo_b    = (ushort_t*)(ws + WS_WO_F);
  ushort_t* theta_b = (ushort_t*)(ws + WS_TH_F);
  ushort_t* phi_b   = (ushort_t*)(ws + WS_PH_F);
  ushort_t* g_b     = (ushort_t*)(ws + WS_G_F);

  sn_kernel<<<4, 256, 0, stream>>>(Wt, Wp, Wg, Wo, ut, up, ug, uo, ws);
  proj_mfma<<<dim3(32, 16), 256, 0, stream>>>(x, wb, theta_b, phi_b, g_b);
  attn_mfma<<<dim3(64, 16), 256, 0, stream>>>(x, theta_b, phi_b, g_b, Wo_b, gamma, out);
}

// Round 2
// 209.178 us; speedup vs baseline: 1.5842x; 1.5706x over previous
//
#include <hip/hip_runtime.h>
#include <math.h>

#define EPS 1e-12f

typedef unsigned short ushort_t;
typedef __attribute__((ext_vector_type(8))) short short8;
typedef __attribute__((ext_vector_type(4))) float f32x4;
typedef __attribute__((ext_vector_type(4))) unsigned short ushort4v;
typedef __attribute__((ext_vector_type(2))) unsigned int uint2v;

// ---- workspace layout (float units) ----
#define WS_WB_F 0
#define WS_WO_F 24576
#define WS_TH_F 40960
#define WS_PH_F 1089536
#define WS_G_F  1351680

__device__ __forceinline__ ushort_t f2bf(float f) {
  unsigned int u = __float_as_uint(f);
  u += 0x7fffu + ((u >> 16) & 1u);
  return (ushort_t)(u >> 16);
}
__device__ __forceinline__ float bf2f(ushort_t u) {
  return __uint_as_float(((unsigned int)u) << 16);
}
__device__ __forceinline__ unsigned int pack_bf2(float lo, float hi) {
  return (unsigned int)f2bf(lo) | ((unsigned int)f2bf(hi) << 16);
}

// async 16B global->LDS DMA (linear LDS dest = wave base + lane*16)
__device__ __forceinline__ void gload_lds16(const ushort_t* g, ushort_t* l) {
  __builtin_amdgcn_global_load_lds(
      (const __attribute__((address_space(1))) unsigned int*)g,
      (__attribute__((address_space(3))) unsigned int*)l, 16, 0, 0);
}

__device__ __forceinline__ float block_reduce_sum(float v, float* red) {
  int t = threadIdx.x;
  red[t] = v;
  __syncthreads();
  #pragma unroll
  for (int s = 128; s > 0; s >>= 1) {
    if (t < s) red[t] += red[t + s];
    __syncthreads();
  }
  float r = red[0];
  __syncthreads();
  return r;
}

// One block per weight: spectral-norm scale, emit bf16 weights in
// MFMA-fragment order (coalesced consumer loads).
__global__ __launch_bounds__(256) void sn_kernel(
    const float* __restrict__ Wt, const float* __restrict__ Wp,
    const float* __restrict__ Wg, const float* __restrict__ Wo,
    const float* __restrict__ ut, const float* __restrict__ up,
    const float* __restrict__ ug, const float* __restrict__ uo,
    float* __restrict__ ws) {
  __shared__ float red[256];
  __shared__ float ub[256];
  __shared__ float vb[256];
  const float* W; const float* u; int O, Ci;
  switch (blockIdx.x) {
    case 0:  W = Wt; u = ut; O = 32;  Ci = 256; break;
    case 1:  W = Wp; u = up; O = 32;  Ci = 256; break;
    case 2:  W = Wg; u = ug; O = 128; Ci = 256; break;
    default: W = Wo; u = uo; O = 256; Ci = 128; break;
  }
  int t = threadIdx.x;
  if (t < O) ub[t] = u[t];
  __syncthreads();
  float tv = 0.f;
  if (t < Ci) {
    for (int o = 0; o < O; o++) tv += W[o * Ci + t] * ub[o];
  }
  float nt2 = block_reduce_sum((t < Ci) ? tv * tv : 0.f, red);
  float ntn = sqrtf(nt2);
  if (t < Ci) vb[t] = tv / (ntn + EPS);
  __syncthreads();
  float sv = 0.f;
  if (t < O) {
    const float* Wr = W + (size_t)t * Ci;
    for (int c = 0; c < Ci; c += 4) {
      float4 wv = *(const float4*)(Wr + c);
      sv += wv.x * vb[c] + wv.y * vb[c + 1] + wv.z * vb[c + 2] + wv.w * vb[c + 3];
    }
  }
  float ss = block_reduce_sum((t < O) ? sv * sv : 0.f, red);
  float ns = sqrtf(ss);
  float sigma = ss / (ns + EPS);
  float inv = 1.f / sigma;
  int total = O * Ci;
  if (blockIdx.x == 3) {
    // Wo fragment order: [(kc*16+oct)*64 + quad*16 + l16]*8 + j
    ushort_t* dst = (ushort_t*)(ws + WS_WO_F);
    for (int i = t; i < total; i += 256) {
      int o = i >> 7, c = i & 127;
      int oct = o >> 4, l16o = o & 15, kc = c >> 5, qd = (c >> 3) & 3, j = c & 7;
      dst[(((kc * 16 + oct) * 64 + qd * 16 + l16o) << 3) + j] = f2bf(W[i] * inv);
    }
  } else {
    // proj fragment order: [(mtg*8+kc)*64 + quad*16 + l16]*8 + j  (mtg global 0..11)
    int base_row = (blockIdx.x == 0) ? 0 : (blockIdx.x == 1 ? 32 : 64);
    ushort_t* dst = (ushort_t*)(ws + WS_WB_F);
    for (int i = t; i < total; i += 256) {
      int o = i >> 8, c = i & 255;
      int og = base_row + o;
      int mtg = og >> 4, l16o = og & 15, kc = c >> 5, qd = (c >> 3) & 3, j = c & 7;
      dst[(((mtg * 8 + kc) * 64 + qd * 16 + l16o) << 3) + j] = f2bf(W[i] * inv);
    }
  }
}

// Fused projection GEMM; weights now read in fragment order (coalesced).
__global__ __launch_bounds__(256, 2) void proj_mfma(
    const float* __restrict__ x, const ushort_t* __restrict__ wb,
    ushort_t* __restrict__ theta_b, ushort_t* __restrict__ phi_b,
    ushort_t* __restrict__ g_b) {
  __shared__ ushort_t xb[128 * 264];
  const int t = threadIdx.x;
  const int n = blockIdx.y;
  const int l0 = blockIdx.x * 128;
  const float* xn = x + ((size_t)n * 256) * 4096 + l0;
  {
    const int lrel = t & 127;
    const int half = t >> 7;
    #pragma unroll 4
    for (int ch = 0; ch < 16; ++ch) {
      int chunk = half * 16 + ch;
      short8 v;
      #pragma unroll
      for (int j = 0; j < 8; ++j) {
        float f = xn[(size_t)(chunk * 8 + j) * 4096 + lrel];
        v[j] = (short)f2bf(f);
      }
      *(short8*)(&xb[lrel * 264 + chunk * 8]) = v;
    }
  }
  __syncthreads();
  const int w = t >> 6;
  const int lane = t & 63;
  const int quad = lane >> 4;
  const int l16 = lane & 15;
  const int rowA = (w * 16 + l16) * 264;
  const int rowB = (64 + w * 16 + l16) * 264;
  const int hd = blockIdx.x;
  #pragma unroll 1
  for (int pass = 0; pass < 2; ++pass) {
    f32x4 accA[6], accB[6];
    #pragma unroll
    for (int i = 0; i < 6; ++i) {
      accA[i] = (f32x4){0.f, 0.f, 0.f, 0.f};
      accB[i] = (f32x4){0.f, 0.f, 0.f, 0.f};
    }
    #pragma unroll
    for (int kc = 0; kc < 8; ++kc) {
      short8 bA = *(const short8*)(&xb[rowA + kc * 32 + quad * 8]);
      short8 bB = *(const short8*)(&xb[rowB + kc * 32 + quad * 8]);
      #pragma unroll
      for (int mt = 0; mt < 6; ++mt) {
        int mtg = pass * 6 + mt;
        short8 aW = *(const short8*)(wb + (((size_t)(mtg * 8 + kc) * 64 + lane) << 3));
        accA[mt] = __builtin_amdgcn_mfma_f32_16x16x32_bf16(aW, bA, accA[mt], 0, 0, 0);
        accB[mt] = __builtin_amdgcn_mfma_f32_16x16x32_bf16(aW, bB, accB[mt], 0, 0, 0);
      }
    }
    #pragma unroll
    for (int mt = 0; mt < 6; ++mt) {
      int mtg = pass * 6 + mt;
      if (mtg < 2) {
        int lA = l0 + w * 16 + l16;
        ushort4v vA, vB;
        #pragma unroll
        for (int r = 0; r < 4; ++r) { vA[r] = f2bf(accA[mt][r]); vB[r] = f2bf(accB[mt][r]); }
        *(ushort4v*)(theta_b + ((size_t)n * 4096 + lA) * 32 + mtg * 16 + quad * 4) = vA;
        *(ushort4v*)(theta_b + ((size_t)n * 4096 + lA + 64) * 32 + mtg * 16 + quad * 4) = vB;
      } else {
        float pm[4];
        #pragma unroll
        for (int r = 0; r < 4; ++r) {
          float v = fmaxf(accA[mt][r], accB[mt][r]);
          v = fmaxf(v, __shfl_xor(v, 1));
          pm[r] = v;
        }
        if ((l16 & 1) == 0) {
          int m = hd * 32 + w * 8 + (l16 >> 1);
          if (mtg < 4) {
            ushort4v vv;
            #pragma unroll
            for (int r = 0; r < 4; ++r) vv[r] = f2bf(pm[r]);
            *(ushort4v*)(phi_b + ((size_t)n * 1024 + m) * 32 + (mtg - 2) * 16 + quad * 4) = vv;
          } else {
            int cg0 = (mtg - 4) * 16 + quad * 4;
            #pragma unroll
            for (int r = 0; r < 4; ++r)
              g_b[((size_t)n * 128 + cg0 + r) * 1024 + m] = f2bf(pm[r]);
          }
        }
      }
    }
  }
}

// Flash attention v3: g staged in LDS per 128-key chunk (global_load_lds,
// XOR-swizzled source / linear dest), S^T scores + lane-local softmax,
// two-pass epilogue with fragment-ordered Wo. outb overlays the g buffer.
__global__ __launch_bounds__(256, 4) void attn_mfma(
    const float* __restrict__ x,
    const ushort_t* __restrict__ theta_b,
    const ushort_t* __restrict__ phi_b,
    const ushort_t* __restrict__ g_b,
    const ushort_t* __restrict__ Wo_fb,
    const float* __restrict__ gamma_p,
    float* __restrict__ out) {
  // [0, 32768)  : g chunk [128 cg][16 slots of 16B], slot XOR-swizzled by row&7
  // [0, 34816)  : outb [256 oc][68 l] bf16 (epilogue overlay)
  // [34816, 39936): pstage, 320 uints per wave
  __shared__ __align__(16) unsigned char smem[39936];
  ushort_t* g_lds = (ushort_t*)smem;
  ushort_t* outb  = (ushort_t*)smem;

  const int t = threadIdx.x;
  const int w = t >> 6;
  const int lane = t & 63;
  const int quad = lane >> 4;
  const int l16 = lane & 15;
  unsigned int* pw = (unsigned int*)(smem + 34816) + w * 320;

  // XCD swizzle: 8 XCDs x 128 blocks; each XCD owns 2 images.
  const int flat = blockIdx.y * 64 + blockIdx.x;
  const int nf = ((flat & 7) << 7) | (flat >> 3);
  const int n = nf >> 6;
  const int l0 = (nf & 63) << 6;
  const int lq = l0 + w * 16;

  const short8 b_th = *(const short8*)(theta_b + ((size_t)n * 4096 + lq + l16) * 32 + quad * 8);
  const ushort_t* phiN = phi_b + (size_t)n * 1024 * 32;
  const ushort_t* gN   = g_b + (size_t)n * 128 * 1024;

  // staging lane constants: instr covers rows 4*blk..+3; lane -> (row_l, slot)
  const int row_l = lane >> 4;          // row within instruction
  const int s_even = (lane & 15) ^ row_l;        // logical slot, b8 even
  // b8 odd: slot = s_even ^ 4

  f32x4 oacc[8];
  #pragma unroll
  for (int j = 0; j < 8; ++j) oacc[j] = (f32x4){0.f, 0.f, 0.f, 0.f};
  float M = -3.0e38f, L = 0.f;

  #pragma unroll 1
  for (int mc = 0; mc < 8; ++mc) {
    const int m0 = mc * 128;
    __syncthreads();   // all waves done reading g_lds (prev chunk)
    // ---- issue g-chunk staging: wave w stages cg rows 32w..32w+31 ----
    #pragma unroll
    for (int b8 = 0; b8 < 8; ++b8) {
      int blk = w * 8 + b8;
      int slot = s_even ^ ((b8 & 1) << 2);
      const ushort_t* src = gN + (size_t)(4 * blk + row_l) * 1024 + m0 + slot * 8;
      gload_lds16(src, g_lds + blk * 512);   // 512 ushorts = 1KB
    }
    // ---- scores S^T (phi from global, coalesced) ----
    f32x4 st[8];
    const f32x4 z = (f32x4){0.f, 0.f, 0.f, 0.f};
    #pragma unroll
    for (int i = 0; i < 8; ++i) {
      short8 aph = *(const short8*)(phiN + (size_t)(m0 + i * 16 + l16) * 32 + quad * 8);
      st[i] = __builtin_amdgcn_mfma_f32_16x16x32_bf16(aph, b_th, z, 0, 0, 0);
    }
    // ---- lane-local online softmax ----
    f32x4 m4 = st[0];
    #pragma unroll
    for (int i = 1; i < 8; ++i) {
      #pragma unroll
      for (int r = 0; r < 4; ++r) m4[r] = fmaxf(m4[r], st[i][r]);
    }
    float mx = fmaxf(fmaxf(m4[0], m4[1]), fmaxf(m4[2], m4[3]));
    mx = fmaxf(mx, __shfl_xor(mx, 16));
    mx = fmaxf(mx, __shfl_xor(mx, 32));
    float nm = fmaxf(M, mx);
    float alpha = __expf(M - nm);
    M = nm;
    #pragma unroll
    for (int i = 0; i < 8; ++i) {
      #pragma unroll
      for (int r = 0; r < 4; ++r) st[i][r] = __expf(st[i][r] - nm);
    }
    f32x4 s4 = st[0];
    #pragma unroll
    for (int i = 1; i < 8; ++i) {
      #pragma unroll
      for (int r = 0; r < 4; ++r) s4[r] += st[i][r];
    }
    float psum = (s4[0] + s4[1]) + (s4[2] + s4[3]);
    psum += __shfl_xor(psum, 16);
    psum += __shfl_xor(psum, 32);
    L = L * alpha + psum;
    #pragma unroll
    for (int j = 0; j < 8; ++j) {
      #pragma unroll
      for (int r = 0; r < 4; ++r) oacc[j][r] *= alpha;
    }
    unsigned int pk[16];
    #pragma unroll
    for (int i = 0; i < 8; ++i) {
      pk[2 * i]     = pack_bf2(st[i][0], st[i][1]);
      pk[2 * i + 1] = pack_bf2(st[i][2], st[i][3]);
    }
    __syncthreads();   // drains vmcnt -> staged g visible to all waves
    // ---- PV from LDS ----
    #pragma unroll
    for (int s = 0; s < 4; ++s) {
      *(uint2v*)&pw[l16 * 20 + quad * 2]     = (uint2v){pk[4 * s],     pk[4 * s + 1]};
      *(uint2v*)&pw[l16 * 20 + 8 + quad * 2] = (uint2v){pk[4 * s + 2], pk[4 * s + 3]};
      short8 pb = *(const short8*)&pw[l16 * 20 + quad * 4];
      #pragma unroll
      for (int j = 0; j < 8; ++j) {
        int row = j * 16 + l16;
        int pslot = (s * 4 + quad) ^ (l16 & 7);
        short8 gf = *(const short8*)(g_lds + row * 128 + pslot * 8);
        oacc[j] = __builtin_amdgcn_mfma_f32_16x16x32_bf16(gf, pb, oacc[j], 0, 0, 0);
      }
    }
  }
  __syncthreads();   // main loop done; g buffer becomes outb

  // ---- epilogue: two oct-halves, acc2[8]; Wo in fragment order ----
  const float invL = 1.f / L;
  #pragma unroll 1
  for (int half = 0; half < 2; ++half) {
    f32x4 acc2[8];
    #pragma unroll
    for (int i = 0; i < 8; ++i) acc2[i] = (f32x4){0.f, 0.f, 0.f, 0.f};
    #pragma unroll
    for (int kc = 0; kc < 4; ++kc) {
      unsigned int e0 = pack_bf2(oacc[2 * kc][0] * invL, oacc[2 * kc][1] * invL);
      unsigned int e1 = pack_bf2(oacc[2 * kc][2] * invL, oacc[2 * kc][3] * invL);
      unsigned int e2 = pack_bf2(oacc[2 * kc + 1][0] * invL, oacc[2 * kc + 1][1] * invL);
      unsigned int e3 = pack_bf2(oacc[2 * kc + 1][2] * invL, oacc[2 * kc + 1][3] * invL);
      *(uint2v*)&pw[l16 * 20 + quad * 2]     = (uint2v){e0, e1};
      *(uint2v*)&pw[l16 * 20 + 8 + quad * 2] = (uint2v){e2, e3};
      short8 aO = *(const short8*)&pw[l16 * 20 + quad * 4];
      #pragma unroll
      for (int o8 = 0; o8 < 8; ++o8) {
        int oct = half * 8 + o8;
        short8 bw = *(const short8*)(Wo_fb + (((size_t)(kc * 16 + oct) * 64 + lane) << 3));
        acc2[o8] = __builtin_amdgcn_mfma_f32_16x16x32_bf16(aO, bw, acc2[o8], 0, 0, 0);
      }
    }
    #pragma unroll
    for (int o8 = 0; o8 < 8; ++o8) {
      int oct = half * 8 + o8;
      #pragma unroll
      for (int r = 0; r < 4; ++r)
        outb[(oct * 16 + l16) * 68 + w * 16 + quad * 4 + r] = f2bf(acc2[o8][r]);
    }
  }
  __syncthreads();
  // ---- residual + coalesced stores ----
  {
    const float gm = gamma_p[0];
    const int oc = (t >> 4);
    const int lch = (t & 15) * 4;
    #pragma unroll
    for (int ocg = 0; ocg < 16; ++ocg) {
      int row = ocg * 16 + oc;
      ushort4v ov = *(const ushort4v*)(&outb[row * 68 + lch]);
      const float* xp = x + ((size_t)n * 256 + row) * 4096 + l0 + lch;
      float* op = out + ((size_t)n * 256 + row) * 4096 + l0 + lch;
      float4 xv = *(const float4*)xp;
      float4 v;
      v.x = xv.x + gm * bf2f(ov[0]);
      v.y = xv.y + gm * bf2f(ov[1]);
      v.z = xv.z + gm * bf2f(ov[2]);
      v.w = xv.w + gm * bf2f(ov[3]);
      *(float4*)op = v;
    }
  }
}

extern "C" void kernel_launch(void* const* d_in, const int* in_sizes, int n_in,
                              void* d_out, int out_size, void* d_ws, size_t ws_size,
                              hipStream_t stream) {
  const float* x  = (const float*)d_in[0];
  const float* Wt = (const float*)d_in[1];
  const float* Wp = (const float*)d_in[2];
  const float* Wg = (const float*)d_in[3];
  const float* Wo = (const float*)d_in[4];
  const float* ut = (const float*)d_in[5];
  const float* up = (const float*)d_in[6];
  const float* ug = (const float*)d_in[7];
  const float* uo = (const float*)d_in[8];
  const float* gamma = (const float*)d_in[9];
  float* ws  = (float*)d_ws;
  float* out = (float*)d_out;

  ushort_t* wb      = (ushort_t*)(ws + WS_WB_F);
  ushort_t* Wo_b    = (ushort_t*)(ws + WS_WO_F);
  ushort_t* theta_b = (ushort_t*)(ws + WS_TH_F);
  ushort_t* phi_b   = (ushort_t*)(ws + WS_PH_F);
  ushort_t* g_b     = (ushort_t*)(ws + WS_G_F);

  sn_kernel<<<4, 256, 0, stream>>>(Wt, Wp, Wg, Wo, ut, up, ug, uo, ws);
  proj_mfma<<<dim3(32, 16), 256, 0, stream>>>(x, wb, theta_b, phi_b, g_b);
  attn_mfma<<<dim3(64, 16), 256, 0, stream>>>(x, theta_b, phi_b, g_b, Wo_b, gamma, out);
}